// Round 11
// baseline (294.667 us; speedup 1.0000x reference)
//
#include <hip/hip_runtime.h>
#include <hip/hip_bf16.h>

typedef __attribute__((ext_vector_type(8))) short bf16x8;
typedef __attribute__((ext_vector_type(4))) float f32x4;

#define D_MODEL 512
#define NHEAD 8
#define HDIM 64
#define SEQ 4096
#define BATCH 2
#define MTOT (BATCH*SEQ)   // 8192
#define NX4 (MTOT*D_MODEL/4)      // x chunks (float4)
#define NW4 (D_MODEL*D_MODEL/4)   // per-weight chunks (float4) = 65536

// Native bf16 convert (RNE); compiler fuses pairs to v_cvt_pk_bf16_f32 (m240:
// scalar cast beats hand-written cvt_pk asm).
__device__ __forceinline__ unsigned short f2bf(float f) {
  return __builtin_bit_cast(unsigned short, __float2bfloat16(f));
}

// ---------------------------------------------------------------------------
// One-shot fp32 -> bf16 convert for x + 4 weights. dst regions are contiguous
// in ws (xb | Wq Wk Wv | Wo) in exactly this source order -> flat dst index.
// ---------------------------------------------------------------------------
__global__ __launch_bounds__(256)
void cvt_all(const float* __restrict__ x,  const float* __restrict__ Wq,
             const float* __restrict__ Wk, const float* __restrict__ Wv,
             const float* __restrict__ Wo, unsigned short* __restrict__ dst) {
  const int total = NX4 + 4*NW4;
  for (int i = blockIdx.x*blockDim.x + threadIdx.x; i < total;
       i += gridDim.x*blockDim.x) {
    const float* src; int off;
    if (i < NX4) { src = x; off = i; }
    else {
      int j = i - NX4;
      off = j & (NW4 - 1);
      int w = j >> 16;                       // NW4 == 2^16
      src = (w == 0) ? Wq : (w == 1) ? Wk : (w == 2) ? Wv : Wo;
    }
    float4 v = ((const float4*)src)[off];
    ushort4 u = { f2bf(v.x), f2bf(v.y), f2bf(v.z), f2bf(v.w) };
    ((ushort4*)dst)[i] = u;
  }
}

// ---------------------------------------------------------------------------
// Fused Q/K/V projection GEMM. Grid (MTOT/128, 12): blockIdx.y>>2 selects
// {Q,K,V}; (blockIdx.y&3)*128 is the 128-wide N-tile within that projection.
// W4 = [Wq;Wk;Wv] contiguous bf16 [3*512,512]. m97 staging structure.
// Q scaled by log2(e)/8 (folds 1/sqrt(Dh) AND the exp2-domain softmax);
// Q,K written [B,H,S,Dh]; V written [B,H,Dh,S] (transposed for PV).
// ---------------------------------------------------------------------------
__global__ __launch_bounds__(256)
void gemm_qkv(const unsigned short* __restrict__ A,
              const unsigned short* __restrict__ W4,
              const float* __restrict__ bq, const float* __restrict__ bk,
              const float* __restrict__ bv,
              unsigned short* __restrict__ qw, unsigned short* __restrict__ kw,
              unsigned short* __restrict__ vtw) {
  __shared__ unsigned short Als[128*64];
  __shared__ unsigned short Bls[128*64];
  const int tid = threadIdx.x;
  const int lane = tid & 63, wid = tid >> 6;
  const int wr = wid >> 1, wc = wid & 1;
  const int l15 = lane & 15, l4 = lane >> 4;
  const int m0 = blockIdx.x * 128;
  const int which = blockIdx.y >> 2;            // 0=Q 1=K 2=V
  const int n0 = (blockIdx.y & 3) * 128;
  const unsigned short* Bw = W4 + (size_t)which * D_MODEL * D_MODEL;
  const float* bias = which == 0 ? bq : (which == 1 ? bk : bv);
  unsigned short* outp = which == 0 ? qw : (which == 1 ? kw : vtw);
  const float scale = which == 0 ? 0.1803368801111204f : 1.0f;  // log2e/8
  const int srow = lane >> 3;
  const int scol = (lane & 7) * 8;
  f32x4 acc[4][4] = {};

  for (int kt = 0; kt < D_MODEL; kt += 64) {
    #pragma unroll
    for (int j = 0; j < 4; ++j) {
      int r = wid*32 + j*8 + srow;
      __builtin_amdgcn_global_load_lds(
        (const __attribute__((address_space(1))) unsigned int*)(A + (size_t)(m0 + r)*D_MODEL + kt + scol),
        (__attribute__((address_space(3))) unsigned int*)(&Als[r*64 + scol]), 16, 0, 0);
      __builtin_amdgcn_global_load_lds(
        (const __attribute__((address_space(1))) unsigned int*)(Bw + (size_t)(n0 + r)*D_MODEL + kt + scol),
        (__attribute__((address_space(3))) unsigned int*)(&Bls[r*64 + scol]), 16, 0, 0);
    }
    __syncthreads();
    #pragma unroll
    for (int ks = 0; ks < 2; ++ks) {
      bf16x8 a[4], b[4];
      #pragma unroll
      for (int m = 0; m < 4; ++m)
        a[m] = *(const bf16x8*)&Als[(wr*64 + m*16 + l15)*64 + ks*32 + l4*8];
      #pragma unroll
      for (int n = 0; n < 4; ++n)
        b[n] = *(const bf16x8*)&Bls[(wc*64 + n*16 + l15)*64 + ks*32 + l4*8];
      #pragma unroll
      for (int m = 0; m < 4; ++m)
        #pragma unroll
        for (int n = 0; n < 4; ++n)
          acc[m][n] = __builtin_amdgcn_mfma_f32_16x16x32_bf16(a[m], b[n], acc[m][n], 0, 0, 0);
    }
    __syncthreads();
  }

  #pragma unroll
  for (int n = 0; n < 4; ++n) {
    int gn = n0 + wc*64 + n*16 + l15;
    float bvv = bias[gn];
    int h = gn >> 6, d = gn & 63;
    #pragma unroll
    for (int m = 0; m < 4; ++m) {
      int gmb = m0 + wr*64 + m*16 + l4*4;
      #pragma unroll
      for (int r = 0; r < 4; ++r) {
        int gm = gmb + r;
        int b = gm >> 12, s = gm & 4095;
        float val = (acc[m][n][r] + bvv) * scale;
        if (which != 2)
          outp[((size_t)((b*NHEAD + h)*SEQ + s))*HDIM + d] = f2bf(val);
        else
          outp[((size_t)((b*NHEAD + h)*HDIM + d))*SEQ + s] = f2bf(val);
      }
    }
  }
}

// ---------------------------------------------------------------------------
// Output-projection GEMM (A bf16 ctx, W bf16, fp32 out [M,N]). m97 structure.
// ---------------------------------------------------------------------------
__global__ __launch_bounds__(256)
void gemm_out(const unsigned short* __restrict__ A,
              const unsigned short* __restrict__ Bw,
              const float* __restrict__ bias, float* __restrict__ out) {
  __shared__ unsigned short Als[128*64];
  __shared__ unsigned short Bls[128*64];
  const int tid = threadIdx.x;
  const int lane = tid & 63, wid = tid >> 6;
  const int wr = wid >> 1, wc = wid & 1;
  const int l15 = lane & 15, l4 = lane >> 4;
  const int m0 = blockIdx.x * 128;
  const int n0 = blockIdx.y * 128;
  const int srow = lane >> 3;
  const int scol = (lane & 7) * 8;
  f32x4 acc[4][4] = {};

  for (int kt = 0; kt < D_MODEL; kt += 64) {
    #pragma unroll
    for (int j = 0; j < 4; ++j) {
      int r = wid*32 + j*8 + srow;
      __builtin_amdgcn_global_load_lds(
        (const __attribute__((address_space(1))) unsigned int*)(A + (size_t)(m0 + r)*D_MODEL + kt + scol),
        (__attribute__((address_space(3))) unsigned int*)(&Als[r*64 + scol]), 16, 0, 0);
      __builtin_amdgcn_global_load_lds(
        (const __attribute__((address_space(1))) unsigned int*)(Bw + (size_t)(n0 + r)*D_MODEL + kt + scol),
        (__attribute__((address_space(3))) unsigned int*)(&Bls[r*64 + scol]), 16, 0, 0);
    }
    __syncthreads();
    #pragma unroll
    for (int ks = 0; ks < 2; ++ks) {
      bf16x8 a[4], b[4];
      #pragma unroll
      for (int m = 0; m < 4; ++m)
        a[m] = *(const bf16x8*)&Als[(wr*64 + m*16 + l15)*64 + ks*32 + l4*8];
      #pragma unroll
      for (int n = 0; n < 4; ++n)
        b[n] = *(const bf16x8*)&Bls[(wc*64 + n*16 + l15)*64 + ks*32 + l4*8];
      #pragma unroll
      for (int m = 0; m < 4; ++m)
        #pragma unroll
        for (int n = 0; n < 4; ++n)
          acc[m][n] = __builtin_amdgcn_mfma_f32_16x16x32_bf16(a[m], b[n], acc[m][n], 0, 0, 0);
    }
    __syncthreads();
  }

  #pragma unroll
  for (int n = 0; n < 4; ++n) {
    int gn = n0 + wc*64 + n*16 + l15;
    float bv = bias[gn];
    #pragma unroll
    for (int m = 0; m < 4; ++m) {
      int gmb = m0 + wr*64 + m*16 + l4*4;
      #pragma unroll
      for (int r = 0; r < 4; ++r)
        out[(size_t)(gmb + r)*D_MODEL + gn] = acc[m][n][r] + bv;
    }
  }
}

// ---------------------------------------------------------------------------
// Flash attention v5: v4 (LDS K/V staging — validated r9: 159us, MfmaUtil 19%,
// VALUBusy 67%) + VALU DIET for the now-dominant softmax pipe:
//  - exp2-domain: S already scaled by log2e at projection -> P = exp2(s - m),
//    one v_exp_f32 per element (saves the ln2 mul). THR 8 -> 11 (2^11 bound).
//  - native __float2bfloat16 (compiler emits v_cvt_pk_bf16_f32; m240).
//  - max trees as nested 3-input fmaxf -> v_max3_f32 (T17).
// Unchanged: swapped-operand math, T1 XCD swizzle, T5 setprio, T13 defer-max,
// source-side XOR-swizzled K/V staging (rule #21), P round-trip via LDS.
// ---------------------------------------------------------------------------
__global__ __launch_bounds__(256)
void attn_k(const unsigned short* __restrict__ qw,
            const unsigned short* __restrict__ kw,
            const unsigned short* __restrict__ vtw,
            unsigned short* __restrict__ ctx) {
  __shared__ unsigned short Kls[64*64];     // [key][d], 16B chunks XOR-swizzled
  __shared__ unsigned short Vls[64*64];     // [d][key], 16B chunks XOR-swizzled
  __shared__ unsigned short Pls[4][16*72];
  const int tid = threadIdx.x;
  const int lane = tid & 63, wid = tid >> 6;
  const int l15 = lane & 15, l4 = lane >> 4;
  const int bid = blockIdx.x;
  const int swz = (bid & 7) * 128 + (bid >> 3);   // bijective: 1024 = 8*128
  const int bh = swz >> 6;                        // b*8 + h, 0..15
  const int q0 = (swz & 63) * 64 + wid * 16;      // this wave's first q row
  const unsigned short* qb = qw + (size_t)bh * SEQ * HDIM;
  const unsigned short* kb = kw + (size_t)bh * SEQ * HDIM;
  const unsigned short* vb = vtw + (size_t)bh * HDIM * SEQ;
  unsigned short* Pw = &Pls[wid][0];

  // staging coords: slot = i*256 + tid; 8 chunks (16B) per 64-elem row
  const int srow0 = tid >> 3;          // slot row for i=0 (0..31)
  const int scol0 = tid & 7;           // chunk col 0..7

  // Q fragments (B-operand): col=l15 <-> q, k=l4*8+j <-> d.
  bf16x8 qf0 = *(const bf16x8*)&qb[(size_t)(q0 + l15)*HDIM + l4*8];
  bf16x8 qf1 = *(const bf16x8*)&qb[(size_t)(q0 + l15)*HDIM + 32 + l4*8];

  f32x4 o[4] = {};                 // o[n][r] = O[d=n*16+l4*4+r][q=l15]
  float mrow = -1e30f, lrow = 0.f; // scalar per lane (one q per lane)

  for (int kt = 0; kt < SEQ; kt += 64) {
    __syncthreads();   // all waves done reading previous tile's K/V
    // ---- stage K,V tile kt: linear LDS dest, XOR-swizzled global source ----
    #pragma unroll
    for (int i = 0; i < 2; ++i) {
      int row = i*32 + srow0;
      int cg = scol0 ^ (row & 7);
      __builtin_amdgcn_global_load_lds(
        (const __attribute__((address_space(1))) unsigned int*)(kb + (size_t)(kt + row)*HDIM + cg*8),
        (__attribute__((address_space(3))) unsigned int*)(&Kls[(i*256 + tid)*8]), 16, 0, 0);
      __builtin_amdgcn_global_load_lds(
        (const __attribute__((address_space(1))) unsigned int*)(vb + (size_t)row*SEQ + kt + cg*8),
        (__attribute__((address_space(3))) unsigned int*)(&Vls[(i*256 + tid)*8]), 16, 0, 0);
    }
    __syncthreads();   // staged data visible (vmcnt drained before barrier)

    // ---- S^T = K Q from LDS (A-frag: row=key=n*16+l15, k=d) ----
    f32x4 s[4] = {};
    __builtin_amdgcn_s_setprio(1);
    #pragma unroll
    for (int n = 0; n < 4; ++n) {
      const int krow = n*16 + l15;
      bf16x8 k0 = *(const bf16x8*)&Kls[krow*64 + ((l4     ^ (l15 & 7))*8)];
      bf16x8 k1 = *(const bf16x8*)&Kls[krow*64 + (((4+l4) ^ (l15 & 7))*8)];
      s[n] = __builtin_amdgcn_mfma_f32_16x16x32_bf16(k0, qf0, s[n], 0, 0, 0);
      s[n] = __builtin_amdgcn_mfma_f32_16x16x32_bf16(k1, qf1, s[n], 0, 0, 0);
    }
    __builtin_amdgcn_s_setprio(0);

    // ---- softmax (log2 domain): max3 trees + 2 shfl ----
    float t0 = fmaxf(fmaxf(s[0][0], s[0][1]), s[0][2]);
    float t1 = fmaxf(fmaxf(s[0][3], s[1][0]), s[1][1]);
    float t2 = fmaxf(fmaxf(s[1][2], s[1][3]), s[2][0]);
    float t3 = fmaxf(fmaxf(s[2][1], s[2][2]), s[2][3]);
    float t4 = fmaxf(fmaxf(s[3][0], s[3][1]), s[3][2]);
    float smax = fmaxf(fmaxf(fmaxf(t0, t1), fmaxf(t2, t3)), fmaxf(t4, s[3][3]));
    smax = fmaxf(smax, __shfl_xor(smax, 16));
    smax = fmaxf(smax, __shfl_xor(smax, 32));
    // T13 defer-max (log2 units; P bounded by 2^11)
    if (__any(smax > mrow + 11.f)) {
      float mn = fmaxf(mrow, smax);
      float alpha = exp2f(mrow - mn);
      mrow = mn;
      lrow *= alpha;
      #pragma unroll
      for (int n = 0; n < 4; ++n)
        #pragma unroll
        for (int r = 0; r < 4; ++r)
          o[n][r] *= alpha;
    }
    #pragma unroll
    for (int n = 0; n < 4; ++n)
      #pragma unroll
      for (int r = 0; r < 4; ++r)
        s[n][r] = exp2f(s[n][r] - mrow);
    float d0 = (s[0][0] + s[0][1]) + (s[0][2] + s[0][3]);
    float d1 = (s[1][0] + s[1][1]) + (s[1][2] + s[1][3]);
    float d2 = (s[2][0] + s[2][1]) + (s[2][2] + s[2][3]);
    float d3 = (s[3][0] + s[3][1]) + (s[3][2] + s[3][3]);
    float rsum = (d0 + d1) + (d2 + d3);
    rsum += __shfl_xor(rsum, 16);
    rsum += __shfl_xor(rsum, 32);
    lrow += rsum;

    // ---- P[q][key] -> LDS: 4x ds_write_b64 (keys l4*4+r consecutive) ----
    #pragma unroll
    for (int n = 0; n < 4; ++n) {
      unsigned int u0 = (unsigned int)f2bf(s[n][0]) | ((unsigned int)f2bf(s[n][1]) << 16);
      unsigned int u1 = (unsigned int)f2bf(s[n][2]) | ((unsigned int)f2bf(s[n][3]) << 16);
      uint2 uu = { u0, u1 };
      *(uint2*)&Pw[l15*72 + n*16 + l4*4] = uu;
    }
    // B-operand fragments: col=l15 <-> q, k=l4*8+j <-> key
    bf16x8 pa0 = *(const bf16x8*)&Pw[l15*72 + l4*8];
    bf16x8 pa1 = *(const bf16x8*)&Pw[l15*72 + 32 + l4*8];

    // ---- O^T += V^T P: V frags JIT from LDS (A-frag: row=d=n*16+l15, k=key)
    __builtin_amdgcn_s_setprio(1);
    #pragma unroll
    for (int n = 0; n < 4; ++n) {
      const int vrow = n*16 + l15;
      bf16x8 v0 = *(const bf16x8*)&Vls[vrow*64 + ((l4     ^ (l15 & 7))*8)];
      bf16x8 v1 = *(const bf16x8*)&Vls[vrow*64 + (((4+l4) ^ (l15 & 7))*8)];
      o[n] = __builtin_amdgcn_mfma_f32_16x16x32_bf16(v0, pa0, o[n], 0, 0, 0);
      o[n] = __builtin_amdgcn_mfma_f32_16x16x32_bf16(v1, pa1, o[n], 0, 0, 0);
    }
    __builtin_amdgcn_s_setprio(0);
  }

  // ---- epilogue: O/l -> ctx [B,S,D_MODEL] bf16, packed ushort4 stores ----
  const int b = bh >> 3, h = bh & 7;
  float inv = 1.0f / lrow;
  #pragma unroll
  for (int n = 0; n < 4; ++n) {
    ushort4 u = { f2bf(o[n][0]*inv), f2bf(o[n][1]*inv),
                  f2bf(o[n][2]*inv), f2bf(o[n][3]*inv) };
    *(ushort4*)&ctx[((size_t)(b*SEQ + q0 + l15))*D_MODEL + h*HDIM + n*16 + l4*4] = u;
  }
}

extern "C" void kernel_launch(void* const* d_in, const int* in_sizes, int n_in,
                              void* d_out, int out_size, void* d_ws, size_t ws_size,
                              hipStream_t stream) {
  const float* x  = (const float*)d_in[0];
  const float* Wq = (const float*)d_in[1];
  const float* bq = (const float*)d_in[2];
  const float* Wk = (const float*)d_in[3];
  const float* bk = (const float*)d_in[4];
  const float* Wv = (const float*)d_in[5];
  const float* bv = (const float*)d_in[6];
  const float* Wo = (const float*)d_in[7];
  const float* bo = (const float*)d_in[8];

  unsigned short* qw  = (unsigned short*)d_ws;                 // [B,H,S,Dh] bf16, 8 MB
  unsigned short* kw  = qw  + (size_t)MTOT*D_MODEL;            // [B,H,S,Dh] bf16, 8 MB
  unsigned short* vtw = kw  + (size_t)MTOT*D_MODEL;            // [B,H,Dh,S] bf16, 8 MB
  unsigned short* ctx = vtw + (size_t)MTOT*D_MODEL;            // [B,S,D]    bf16, 8 MB
  unsigned short* xb  = ctx + (size_t)MTOT*D_MODEL;            // [M,512]    bf16, 8 MB
  unsigned short* wqb = xb  + (size_t)MTOT*D_MODEL;            // 3x [512,512] bf16 (Wq,Wk,Wv)
  unsigned short* wob = wqb + 3*(size_t)D_MODEL*D_MODEL;       // [512,512] bf16 (Wo)

  dim3 bb(256);
  cvt_all<<<2048, bb, 0, stream>>>(x, Wq, Wk, Wv, Wo, xb);

  gemm_qkv<<<dim3(MTOT/128, 12), bb, 0, stream>>>(xb, wqb, bq, bk, bv, qw, kw, vtw);
  attn_k<<<dim3(SEQ/64 * BATCH*NHEAD), bb, 0, stream>>>(qw, kw, vtw, ctx);
  gemm_out<<<dim3(MTOT/128, D_MODEL/128), bb, 0, stream>>>(ctx, wob, bo, (float*)d_out);
}

// Round 13
// 261.655 us; speedup vs baseline: 1.1262x; 1.1262x over previous
//
#include <hip/hip_runtime.h>
#include <hip/hip_bf16.h>

typedef __attribute__((ext_vector_type(8))) short bf16x8;
typedef __attribute__((ext_vector_type(4))) float f32x4;

#define D_MODEL 512
#define NHEAD 8
#define HDIM 64
#define SEQ 4096
#define BATCH 2
#define MTOT (BATCH*SEQ)   // 8192
#define NX4 (MTOT*D_MODEL/4)      // x chunks (float4)
#define NW4 (D_MODEL*D_MODEL/4)   // per-weight chunks (float4) = 65536

// Manual RNE fp32->bf16 (4 ops, NO NaN branch — r9-proven; __float2bfloat16's
// NaN-handling branch cost ~2 ops/elem, r11 regression).
__device__ __forceinline__ unsigned short f2bf(float f) {
  unsigned int u = __builtin_bit_cast(unsigned int, f);
  u += 0x7FFFu + ((u >> 16) & 1u);
  return (unsigned short)(u >> 16);
}

// Raw v_exp_f32: computes 2^x in 1 inst (libm exp2f = OCML precise path with
// denorm fixup, ~5 ops — the r11 regression). Flush-to-zero on big-negative
// input is exactly right for online softmax.
__device__ __forceinline__ float exp2_raw(float x) {
  float r;
  asm("v_exp_f32 %0, %1" : "=v"(r) : "v"(x));
  return r;
}

// ---------------------------------------------------------------------------
// One-shot fp32 -> bf16 convert for x + 4 weights. dst regions are contiguous
// in ws (xb | Wq Wk Wv | Wo) in exactly this source order -> flat dst index.
// ---------------------------------------------------------------------------
__global__ __launch_bounds__(256)
void cvt_all(const float* __restrict__ x,  const float* __restrict__ Wq,
             const float* __restrict__ Wk, const float* __restrict__ Wv,
             const float* __restrict__ Wo, unsigned short* __restrict__ dst) {
  const int total = NX4 + 4*NW4;
  for (int i = blockIdx.x*blockDim.x + threadIdx.x; i < total;
       i += gridDim.x*blockDim.x) {
    const float* src; int off;
    if (i < NX4) { src = x; off = i; }
    else {
      int j = i - NX4;
      off = j & (NW4 - 1);
      int w = j >> 16;                       // NW4 == 2^16
      src = (w == 0) ? Wq : (w == 1) ? Wk : (w == 2) ? Wv : Wo;
    }
    float4 v = ((const float4*)src)[off];
    ushort4 u = { f2bf(v.x), f2bf(v.y), f2bf(v.z), f2bf(v.w) };
    ((ushort4*)dst)[i] = u;
  }
}

// ---------------------------------------------------------------------------
// Fused Q/K/V projection GEMM. Grid (MTOT/128, 12): blockIdx.y>>2 selects
// {Q,K,V}; (blockIdx.y&3)*128 is the 128-wide N-tile within that projection.
// W4 = [Wq;Wk;Wv] contiguous bf16 [3*512,512]. m97 staging structure.
// Q scaled by log2(e)/8 (folds 1/sqrt(Dh) AND the exp2-domain softmax);
// Q,K written [B,H,S,Dh]; V written [B,H,Dh,S] (transposed for PV).
// ---------------------------------------------------------------------------
__global__ __launch_bounds__(256)
void gemm_qkv(const unsigned short* __restrict__ A,
              const unsigned short* __restrict__ W4,
              const float* __restrict__ bq, const float* __restrict__ bk,
              const float* __restrict__ bv,
              unsigned short* __restrict__ qw, unsigned short* __restrict__ kw,
              unsigned short* __restrict__ vtw) {
  __shared__ unsigned short Als[128*64];
  __shared__ unsigned short Bls[128*64];
  const int tid = threadIdx.x;
  const int lane = tid & 63, wid = tid >> 6;
  const int wr = wid >> 1, wc = wid & 1;
  const int l15 = lane & 15, l4 = lane >> 4;
  const int m0 = blockIdx.x * 128;
  const int which = blockIdx.y >> 2;            // 0=Q 1=K 2=V
  const int n0 = (blockIdx.y & 3) * 128;
  const unsigned short* Bw = W4 + (size_t)which * D_MODEL * D_MODEL;
  const float* bias = which == 0 ? bq : (which == 1 ? bk : bv);
  unsigned short* outp = which == 0 ? qw : (which == 1 ? kw : vtw);
  const float scale = which == 0 ? 0.1803368801111204f : 1.0f;  // log2e/8
  const int srow = lane >> 3;
  const int scol = (lane & 7) * 8;
  f32x4 acc[4][4] = {};

  for (int kt = 0; kt < D_MODEL; kt += 64) {
    #pragma unroll
    for (int j = 0; j < 4; ++j) {
      int r = wid*32 + j*8 + srow;
      __builtin_amdgcn_global_load_lds(
        (const __attribute__((address_space(1))) unsigned int*)(A + (size_t)(m0 + r)*D_MODEL + kt + scol),
        (__attribute__((address_space(3))) unsigned int*)(&Als[r*64 + scol]), 16, 0, 0);
      __builtin_amdgcn_global_load_lds(
        (const __attribute__((address_space(1))) unsigned int*)(Bw + (size_t)(n0 + r)*D_MODEL + kt + scol),
        (__attribute__((address_space(3))) unsigned int*)(&Bls[r*64 + scol]), 16, 0, 0);
    }
    __syncthreads();
    #pragma unroll
    for (int ks = 0; ks < 2; ++ks) {
      bf16x8 a[4], b[4];
      #pragma unroll
      for (int m = 0; m < 4; ++m)
        a[m] = *(const bf16x8*)&Als[(wr*64 + m*16 + l15)*64 + ks*32 + l4*8];
      #pragma unroll
      for (int n = 0; n < 4; ++n)
        b[n] = *(const bf16x8*)&Bls[(wc*64 + n*16 + l15)*64 + ks*32 + l4*8];
      #pragma unroll
      for (int m = 0; m < 4; ++m)
        #pragma unroll
        for (int n = 0; n < 4; ++n)
          acc[m][n] = __builtin_amdgcn_mfma_f32_16x16x32_bf16(a[m], b[n], acc[m][n], 0, 0, 0);
    }
    __syncthreads();
  }

  #pragma unroll
  for (int n = 0; n < 4; ++n) {
    int gn = n0 + wc*64 + n*16 + l15;
    float bvv = bias[gn];
    int h = gn >> 6, d = gn & 63;
    #pragma unroll
    for (int m = 0; m < 4; ++m) {
      int gmb = m0 + wr*64 + m*16 + l4*4;
      #pragma unroll
      for (int r = 0; r < 4; ++r) {
        int gm = gmb + r;
        int b = gm >> 12, s = gm & 4095;
        float val = (acc[m][n][r] + bvv) * scale;
        if (which != 2)
          outp[((size_t)((b*NHEAD + h)*SEQ + s))*HDIM + d] = f2bf(val);
        else
          outp[((size_t)((b*NHEAD + h)*HDIM + d))*SEQ + s] = f2bf(val);
      }
    }
  }
}

// ---------------------------------------------------------------------------
// Output-projection GEMM (A bf16 ctx, W bf16, fp32 out [M,N]). m97 structure.
// ---------------------------------------------------------------------------
__global__ __launch_bounds__(256)
void gemm_out(const unsigned short* __restrict__ A,
              const unsigned short* __restrict__ Bw,
              const float* __restrict__ bias, float* __restrict__ out) {
  __shared__ unsigned short Als[128*64];
  __shared__ unsigned short Bls[128*64];
  const int tid = threadIdx.x;
  const int lane = tid & 63, wid = tid >> 6;
  const int wr = wid >> 1, wc = wid & 1;
  const int l15 = lane & 15, l4 = lane >> 4;
  const int m0 = blockIdx.x * 128;
  const int n0 = blockIdx.y * 128;
  const int srow = lane >> 3;
  const int scol = (lane & 7) * 8;
  f32x4 acc[4][4] = {};

  for (int kt = 0; kt < D_MODEL; kt += 64) {
    #pragma unroll
    for (int j = 0; j < 4; ++j) {
      int r = wid*32 + j*8 + srow;
      __builtin_amdgcn_global_load_lds(
        (const __attribute__((address_space(1))) unsigned int*)(A + (size_t)(m0 + r)*D_MODEL + kt + scol),
        (__attribute__((address_space(3))) unsigned int*)(&Als[r*64 + scol]), 16, 0, 0);
      __builtin_amdgcn_global_load_lds(
        (const __attribute__((address_space(1))) unsigned int*)(Bw + (size_t)(n0 + r)*D_MODEL + kt + scol),
        (__attribute__((address_space(3))) unsigned int*)(&Bls[r*64 + scol]), 16, 0, 0);
    }
    __syncthreads();
    #pragma unroll
    for (int ks = 0; ks < 2; ++ks) {
      bf16x8 a[4], b[4];
      #pragma unroll
      for (int m = 0; m < 4; ++m)
        a[m] = *(const bf16x8*)&Als[(wr*64 + m*16 + l15)*64 + ks*32 + l4*8];
      #pragma unroll
      for (int n = 0; n < 4; ++n)
        b[n] = *(const bf16x8*)&Bls[(wc*64 + n*16 + l15)*64 + ks*32 + l4*8];
      #pragma unroll
      for (int m = 0; m < 4; ++m)
        #pragma unroll
        for (int n = 0; n < 4; ++n)
          acc[m][n] = __builtin_amdgcn_mfma_f32_16x16x32_bf16(a[m], b[n], acc[m][n], 0, 0, 0);
    }
    __syncthreads();
  }

  #pragma unroll
  for (int n = 0; n < 4; ++n) {
    int gn = n0 + wc*64 + n*16 + l15;
    float bv = bias[gn];
    #pragma unroll
    for (int m = 0; m < 4; ++m) {
      int gmb = m0 + wr*64 + m*16 + l4*4;
      #pragma unroll
      for (int r = 0; r < 4; ++r)
        out[(size_t)(gmb + r)*D_MODEL + gn] = acc[m][n][r] + bv;
    }
  }
}

// ---------------------------------------------------------------------------
// Flash attention v6: v4 structure (LDS K/V staging, r9: 159us) + VALU diet
// done with the RIGHT instructions (r11 used libm exp2f + __float2bfloat16,
// both SLOWER than intended — VALUBusy 67->72%, 159->182us):
//  - exp2 via raw v_exp_f32 asm (1 inst; log2e folded into Q scale).
//  - P pack via v_cvt_pk_bf16_f32 asm (T12 recipe, dst.lo=src0): 8 inst/tile
//    replaces 16 converts + 8 or/shifts.
//  - f2bf manual RNE everywhere else (no NaN branch).
// Unchanged: swapped-operand math, T1 XCD swizzle, T5 setprio, T13 defer-max
// (THR=11 log2-units), source-side XOR-swizzled staging (rule #21), max3
// trees, P round-trip via LDS.
// ---------------------------------------------------------------------------
__global__ __launch_bounds__(256)
void attn_k(const unsigned short* __restrict__ qw,
            const unsigned short* __restrict__ kw,
            const unsigned short* __restrict__ vtw,
            unsigned short* __restrict__ ctx) {
  __shared__ unsigned short Kls[64*64];     // [key][d], 16B chunks XOR-swizzled
  __shared__ unsigned short Vls[64*64];     // [d][key], 16B chunks XOR-swizzled
  __shared__ unsigned short Pls[4][16*72];
  const int tid = threadIdx.x;
  const int lane = tid & 63, wid = tid >> 6;
  const int l15 = lane & 15, l4 = lane >> 4;
  const int bid = blockIdx.x;
  const int swz = (bid & 7) * 128 + (bid >> 3);   // bijective: 1024 = 8*128
  const int bh = swz >> 6;                        // b*8 + h, 0..15
  const int q0 = (swz & 63) * 64 + wid * 16;      // this wave's first q row
  const unsigned short* qb = qw + (size_t)bh * SEQ * HDIM;
  const unsigned short* kb = kw + (size_t)bh * SEQ * HDIM;
  const unsigned short* vb = vtw + (size_t)bh * HDIM * SEQ;
  unsigned short* Pw = &Pls[wid][0];

  // staging coords: slot = i*256 + tid; 8 chunks (16B) per 64-elem row
  const int srow0 = tid >> 3;          // slot row for i=0 (0..31)
  const int scol0 = tid & 7;           // chunk col 0..7

  // Q fragments (B-operand): col=l15 <-> q, k=l4*8+j <-> d.
  bf16x8 qf0 = *(const bf16x8*)&qb[(size_t)(q0 + l15)*HDIM + l4*8];
  bf16x8 qf1 = *(const bf16x8*)&qb[(size_t)(q0 + l15)*HDIM + 32 + l4*8];

  f32x4 o[4] = {};                 // o[n][r] = O[d=n*16+l4*4+r][q=l15]
  float mrow = -1e30f, lrow = 0.f; // scalar per lane (one q per lane)

  for (int kt = 0; kt < SEQ; kt += 64) {
    __syncthreads();   // all waves done reading previous tile's K/V
    // ---- stage K,V tile kt: linear LDS dest, XOR-swizzled global source ----
    #pragma unroll
    for (int i = 0; i < 2; ++i) {
      int row = i*32 + srow0;
      int cg = scol0 ^ (row & 7);
      __builtin_amdgcn_global_load_lds(
        (const __attribute__((address_space(1))) unsigned int*)(kb + (size_t)(kt + row)*HDIM + cg*8),
        (__attribute__((address_space(3))) unsigned int*)(&Kls[(i*256 + tid)*8]), 16, 0, 0);
      __builtin_amdgcn_global_load_lds(
        (const __attribute__((address_space(1))) unsigned int*)(vb + (size_t)row*SEQ + kt + cg*8),
        (__attribute__((address_space(3))) unsigned int*)(&Vls[(i*256 + tid)*8]), 16, 0, 0);
    }
    __syncthreads();   // staged data visible (vmcnt drained before barrier)

    // ---- S^T = K Q from LDS (A-frag: row=key=n*16+l15, k=d) ----
    f32x4 s[4] = {};
    __builtin_amdgcn_s_setprio(1);
    #pragma unroll
    for (int n = 0; n < 4; ++n) {
      const int krow = n*16 + l15;
      bf16x8 k0 = *(const bf16x8*)&Kls[krow*64 + ((l4     ^ (l15 & 7))*8)];
      bf16x8 k1 = *(const bf16x8*)&Kls[krow*64 + (((4+l4) ^ (l15 & 7))*8)];
      s[n] = __builtin_amdgcn_mfma_f32_16x16x32_bf16(k0, qf0, s[n], 0, 0, 0);
      s[n] = __builtin_amdgcn_mfma_f32_16x16x32_bf16(k1, qf1, s[n], 0, 0, 0);
    }
    __builtin_amdgcn_s_setprio(0);

    // ---- softmax (log2 domain): max3 trees + 2 shfl ----
    float t0 = fmaxf(fmaxf(s[0][0], s[0][1]), s[0][2]);
    float t1 = fmaxf(fmaxf(s[0][3], s[1][0]), s[1][1]);
    float t2 = fmaxf(fmaxf(s[1][2], s[1][3]), s[2][0]);
    float t3 = fmaxf(fmaxf(s[2][1], s[2][2]), s[2][3]);
    float t4 = fmaxf(fmaxf(s[3][0], s[3][1]), s[3][2]);
    float smax = fmaxf(fmaxf(fmaxf(t0, t1), fmaxf(t2, t3)), fmaxf(t4, s[3][3]));
    smax = fmaxf(smax, __shfl_xor(smax, 16));
    smax = fmaxf(smax, __shfl_xor(smax, 32));
    // T13 defer-max (log2 units; P bounded by 2^11)
    if (__any(smax > mrow + 11.f)) {
      float mn = fmaxf(mrow, smax);
      float alpha = exp2_raw(mrow - mn);
      mrow = mn;
      lrow *= alpha;
      #pragma unroll
      for (int n = 0; n < 4; ++n)
        #pragma unroll
        for (int r = 0; r < 4; ++r)
          o[n][r] *= alpha;
    }
    #pragma unroll
    for (int n = 0; n < 4; ++n)
      #pragma unroll
      for (int r = 0; r < 4; ++r)
        s[n][r] = exp2_raw(s[n][r] - mrow);
    float d0 = (s[0][0] + s[0][1]) + (s[0][2] + s[0][3]);
    float d1 = (s[1][0] + s[1][1]) + (s[1][2] + s[1][3]);
    float d2 = (s[2][0] + s[2][1]) + (s[2][2] + s[2][3]);
    float d3 = (s[3][0] + s[3][1]) + (s[3][2] + s[3][3]);
    float rsum = (d0 + d1) + (d2 + d3);
    rsum += __shfl_xor(rsum, 16);
    rsum += __shfl_xor(rsum, 32);
    lrow += rsum;

    // ---- P[q][key] -> LDS: v_cvt_pk + 4x ds_write_b64 ----
    #pragma unroll
    for (int n = 0; n < 4; ++n) {
      unsigned int u0, u1;
      asm("v_cvt_pk_bf16_f32 %0, %1, %2" : "=v"(u0) : "v"(s[n][0]), "v"(s[n][1]));
      asm("v_cvt_pk_bf16_f32 %0, %1, %2" : "=v"(u1) : "v"(s[n][2]), "v"(s[n][3]));
      uint2 uu = { u0, u1 };
      *(uint2*)&Pw[l15*72 + n*16 + l4*4] = uu;
    }
    // B-operand fragments: col=l15 <-> q, k=l4*8+j <-> key
    bf16x8 pa0 = *(const bf16x8*)&Pw[l15*72 + l4*8];
    bf16x8 pa1 = *(const bf16x8*)&Pw[l15*72 + 32 + l4*8];

    // ---- O^T += V^T P: V frags JIT from LDS (A-frag: row=d=n*16+l15, k=key)
    __builtin_amdgcn_s_setprio(1);
    #pragma unroll
    for (int n = 0; n < 4; ++n) {
      const int vrow = n*16 + l15;
      bf16x8 v0 = *(const bf16x8*)&Vls[vrow*64 + ((l4     ^ (l15 & 7))*8)];
      bf16x8 v1 = *(const bf16x8*)&Vls[vrow*64 + (((4+l4) ^ (l15 & 7))*8)];
      o[n] = __builtin_amdgcn_mfma_f32_16x16x32_bf16(v0, pa0, o[n], 0, 0, 0);
      o[n] = __builtin_amdgcn_mfma_f32_16x16x32_bf16(v1, pa1, o[n], 0, 0, 0);
    }
    __builtin_amdgcn_s_setprio(0);
  }

  // ---- epilogue: O/l -> ctx [B,S,D_MODEL] bf16, packed ushort4 stores ----
  const int b = bh >> 3, h = bh & 7;
  float inv = 1.0f / lrow;
  #pragma unroll
  for (int n = 0; n < 4; ++n) {
    ushort4 u = { f2bf(o[n][0]*inv), f2bf(o[n][1]*inv),
                  f2bf(o[n][2]*inv), f2bf(o[n][3]*inv) };
    *(ushort4*)&ctx[((size_t)(b*SEQ + q0 + l15))*D_MODEL + h*HDIM + n*16 + l4*4] = u;
  }
}

extern "C" void kernel_launch(void* const* d_in, const int* in_sizes, int n_in,
                              void* d_out, int out_size, void* d_ws, size_t ws_size,
                              hipStream_t stream) {
  const float* x  = (const float*)d_in[0];
  const float* Wq = (const float*)d_in[1];
  const float* bq = (const float*)d_in[2];
  const float* Wk = (const float*)d_in[3];
  const float* bk = (const float*)d_in[4];
  const float* Wv = (const float*)d_in[5];
  const float* bv = (const float*)d_in[6];
  const float* Wo = (const float*)d_in[7];
  const float* bo = (const float*)d_in[8];

  unsigned short* qw  = (unsigned short*)d_ws;                 // [B,H,S,Dh] bf16, 8 MB
  unsigned short* kw  = qw  + (size_t)MTOT*D_MODEL;            // [B,H,S,Dh] bf16, 8 MB
  unsigned short* vtw = kw  + (size_t)MTOT*D_MODEL;            // [B,H,Dh,S] bf16, 8 MB
  unsigned short* ctx = vtw + (size_t)MTOT*D_MODEL;            // [B,S,D]    bf16, 8 MB
  unsigned short* xb  = ctx + (size_t)MTOT*D_MODEL;            // [M,512]    bf16, 8 MB
  unsigned short* wqb = xb  + (size_t)MTOT*D_MODEL;            // 3x [512,512] bf16 (Wq,Wk,Wv)
  unsigned short* wob = wqb + 3*(size_t)D_MODEL*D_MODEL;       // [512,512] bf16 (Wo)

  dim3 bb(256);
  cvt_all<<<2048, bb, 0, stream>>>(x, Wq, Wk, Wv, Wo, xb);

  gemm_qkv<<<dim3(MTOT/128, 12), bb, 0, stream>>>(xb, wqb, bq, bk, bv, qw, kw, vtw);
  attn_k<<<dim3(SEQ/64 * BATCH*NHEAD), bb, 0, stream>>>(qw, kw, vtw, ctx);
  gemm_out<<<dim3(MTOT/128, D_MODEL/128), bb, 0, stream>>>(ctx, wob, bo, (float*)d_out);
}